// Round 7
// baseline (224.849 us; speedup 1.0000x reference)
//
#include <hip/hip_runtime.h>
#include <hip/hip_fp16.h>

static __device__ __forceinline__ float gelu(float x) {
    return 0.5f * x * (1.0f + erff(x * 0.70710678118654752f));
}

#define CAPR 32   // slots per replica (2 replicas/node, Poisson(8) -> safe)

typedef _Float16 v8h __attribute__((ext_vector_type(8)));
typedef float    v4f __attribute__((ext_vector_type(4)));
typedef int      v4i __attribute__((ext_vector_type(4)));
union F8 { uint4 u; v8h v; _Float16 f[8]; };

static __device__ __forceinline__ void acc8(float* a, uint4 u) {
    float2 f0 = __half22float2(*(__half2*)&u.x);
    float2 f1 = __half22float2(*(__half2*)&u.y);
    float2 f2 = __half22float2(*(__half2*)&u.z);
    float2 f3 = __half22float2(*(__half2*)&u.w);
    a[0] += f0.x; a[1] += f0.y; a[2] += f1.x; a[3] += f1.y;
    a[4] += f2.x; a[5] += f2.y; a[6] += f3.x; a[7] += f3.y;
}

static __device__ __forceinline__ uint4 pack8(const float* v) {
    __half2 p0 = __floats2half2_rn(v[0], v[1]);
    __half2 p1 = __floats2half2_rn(v[2], v[3]);
    __half2 p2 = __floats2half2_rn(v[4], v[5]);
    __half2 p3 = __floats2half2_rn(v[6], v[7]);
    uint4 u;
    u.x = *(unsigned*)&p0; u.y = *(unsigned*)&p1;
    u.z = *(unsigned*)&p2; u.w = *(unsigned*)&p3;
    return u;
}

// ---- v7: revert scatter to the best-measured r2/r4 structure (merged
//      XCD-partitioned filter-scatter + encoder, nt ei loads, 206us).
//      Six rounds of counters showed scatter reshuffles are +-noise;
//      gather+updec (~85us, never profiled) is the unattacked budget. ----
__global__ void __launch_bounds__(256, 4)
k_enc_scat(const float* __restrict__ x,
           const float* __restrict__ grid,
           const float* __restrict__ W1,
           const float* __restrict__ b1,
           const float* __restrict__ W2,
           const float* __restrict__ b2,
           const int* __restrict__ ei, int* __restrict__ cnt,
           unsigned short* __restrict__ ssrc,
           __half* __restrict__ h16, int N, int E, int scatB)
{
    __shared__ uint4 tabW2[1024];           // 16 KB
    __shared__ __half wmids[4 * 16 * 136];  // 17 KB
    int tid = threadIdx.x;

    if ((int)blockIdx.x < scatB) {
        int p = blockIdx.x & 7;             // dst partition (== XCD via %8 round-robin)
        int c = blockIdx.x >> 3;            // edge chunk
        const v4i* s4 = (const v4i*)ei;
        const v4i* d4 = (const v4i*)(ei + E);
        int g4 = (E / (scatB >> 3)) >> 2;   // int4 groups per chunk (2048)
        int base4 = c * g4;
        int shift = 31 - __clz(N >> 3);     // log2(N/8) = 13
#pragma unroll 8
        for (int g = 0; g < g4 / 256; g++) {
            int idx = base4 + g * 256 + tid;
            v4i d = __builtin_nontemporal_load(&d4[idx]);
            v4i s = __builtin_nontemporal_load(&s4[idx]);
            int q;
            if ((d[0] >> shift) == p) {
                q = atomicAdd(&cnt[(d[0] << 1) + 0], 1);
                if (q < CAPR) ssrc[((size_t)d[0] << 6) + q] = (unsigned short)s[0];
            }
            if ((d[1] >> shift) == p) {
                q = atomicAdd(&cnt[(d[1] << 1) + 1], 1);
                if (q < CAPR) ssrc[((size_t)d[1] << 6) + 32 + q] = (unsigned short)s[1];
            }
            if ((d[2] >> shift) == p) {
                q = atomicAdd(&cnt[(d[2] << 1) + 0], 1);
                if (q < CAPR) ssrc[((size_t)d[2] << 6) + q] = (unsigned short)s[2];
            }
            if ((d[3] >> shift) == p) {
                q = atomicAdd(&cnt[(d[3] << 1) + 1], 1);
                if (q < CAPR) ssrc[((size_t)d[3] << 6) + 32 + q] = (unsigned short)s[3];
            }
        }
        return;
    }

    // ---- encoder ----
    int eb = blockIdx.x - scatB;
    int lane = tid & 63, wave = tid >> 6;
    int m = lane & 15, quad = lane >> 4;

    F8 w1f[8];
#pragma unroll
    for (int nt = 0; nt < 8; nt++) {
        int col = nt * 16 + m;
        int k0 = quad << 3;
#pragma unroll
        for (int j = 0; j < 8; j++)
            w1f[nt].f[j] = (k0 + j < 12) ? (_Float16)W1[(k0 + j) * 128 + col] : (_Float16)0.f;
    }

    for (int idx = tid; idx < 1024; idx += 256) {     // W2 frags
        int l2 = idx & 63, nt = (idx >> 6) & 3, kc = idx >> 8;
        int col = nt * 16 + (l2 & 15);
        int k0 = kc * 32 + ((l2 >> 4) << 3);
        F8 f;
#pragma unroll
        for (int j = 0; j < 8; j++) f.f[j] = (_Float16)W2[(k0 + j) * 64 + col];
        tabW2[idx] = f.u;
    }
    __syncthreads();

    __half* wm = &wmids[wave * 16 * 136];

    for (int t = 0; t < 2; t++) {
        int tile = eb * 8 + wave * 2 + t;
        int base = tile * 16;
        int n = base + m;
        F8 a1;
#pragma unroll
        for (int j = 0; j < 8; j++) a1.f[j] = (_Float16)0.f;
        if (quad == 0) {
            float2 x0 = *(const float2*)&x[(size_t)n * 10 + 0];
            float2 x1 = *(const float2*)&x[(size_t)n * 10 + 2];
            float2 x2 = *(const float2*)&x[(size_t)n * 10 + 4];
            float2 x3 = *(const float2*)&x[(size_t)n * 10 + 6];
            a1.f[0] = (_Float16)x0.x; a1.f[1] = (_Float16)x0.y;
            a1.f[2] = (_Float16)x1.x; a1.f[3] = (_Float16)x1.y;
            a1.f[4] = (_Float16)x2.x; a1.f[5] = (_Float16)x2.y;
            a1.f[6] = (_Float16)x3.x; a1.f[7] = (_Float16)x3.y;
        } else if (quad == 1) {
            float2 x4 = *(const float2*)&x[(size_t)n * 10 + 8];
            float2 g  = *(const float2*)&grid[(size_t)n * 2];
            a1.f[0] = (_Float16)x4.x; a1.f[1] = (_Float16)x4.y;
            a1.f[2] = (_Float16)g.x;  a1.f[3] = (_Float16)g.y;
        }
#pragma unroll
        for (int nt = 0; nt < 8; nt++) {
            int col = nt * 16 + m;
            float b = b1[col];
            v4f acc = {b, b, b, b};
            acc = __builtin_amdgcn_mfma_f32_16x16x32_f16(a1.v, w1f[nt].v, acc, 0, 0, 0);
#pragma unroll
            for (int reg = 0; reg < 4; reg++)
                wm[(quad * 4 + reg) * 136 + col] = __float2half(gelu(acc[reg]));
        }
        __syncthreads();

        F8 a2[4];
#pragma unroll
        for (int kc = 0; kc < 4; kc++)
            a2[kc].u = *(const uint4*)&wm[m * 136 + kc * 32 + quad * 8];
#pragma unroll
        for (int nt = 0; nt < 4; nt++) {
            int col = nt * 16 + m;
            float b = b2[col];
            v4f acc = {b, b, b, b};
#pragma unroll
            for (int kc = 0; kc < 4; kc++) {
                F8 bf; bf.u = tabW2[kc * 256 + nt * 64 + lane];
                acc = __builtin_amdgcn_mfma_f32_16x16x32_f16(a2[kc].v, bf.v, acc, 0, 0, 0);
            }
#pragma unroll
            for (int reg = 0; reg < 4; reg++)
                h16[(size_t)(base + quad * 4 + reg) * 64 + col] = __float2half(acc[reg]);
        }
        __syncthreads();
    }
}

// ---- v7: k_gupdec = gather FUSED into update+decode. Lane (quad,m) gathers
//      h16 chunks quad and quad+4 of node base+m -> the gather sum lands in
//      registers ALREADY in the as0/as1 MFMA A-frag layout. Deletes sum_h16
//      (8MB w + 8MB r), sum_g/sum_d round-trips, pack/unpack, and the 512K-
//      thread k_gather launch. 1 tile/wave x 1024 blocks (vs 8 tiles/block
//      x 512) for occupancy during the latency-bound gather phase; tabV in
//      registers (-4KB LDS -> 49KB, 3 blocks/CU). ----
__global__ void __launch_bounds__(256, 1)
k_gupdec(const __half* __restrict__ h16,
         const unsigned short* __restrict__ ssrc,
         const int* __restrict__ cnt, const float* __restrict__ grid,
         const float* __restrict__ Wk, const float* __restrict__ bk,
         const float* __restrict__ Ww, const float* __restrict__ bw,
         const float* __restrict__ Wd1, const float* __restrict__ bd1,
         const float* __restrict__ Wd2, const float* __restrict__ bd2,
         float* __restrict__ out, int N)
{
    __shared__ uint4 tabW[512];             // 8 KB  Ww
    __shared__ uint4 tabC[512];             // 8 KB  WkC
    __shared__ uint4 tabD[512];             // 8 KB  WkD
    __shared__ uint4 tabE[1024];            // 16 KB Wd1
    __shared__ __half h2t[4 * 16 * 72];     // 9 KB  per-wave h2 tile (stride 72)
    int tid = threadIdx.x;
    int lane = tid & 63, wave = tid >> 6;
    int m = lane & 15, quad = lane >> 4;

    for (int idx = tid; idx < 512; idx += 256) {
        int l2 = idx & 63, nt = (idx >> 6) & 3, kc = idx >> 8;
        int col = nt * 16 + (l2 & 15);
        int kr  = kc * 32 + ((l2 >> 4) << 3);
        F8 fw, fc, fd;
#pragma unroll
        for (int j = 0; j < 8; j++) {
            fw.f[j] = (_Float16)Ww[(kr + j) * 64 + col];
            fc.f[j] = (_Float16)Wk[(size_t)(5 + kr + j) * 64 + col];
            fd.f[j] = (_Float16)Wk[(size_t)(69 + kr + j) * 64 + col];
        }
        tabW[idx] = fw.u; tabC[idx] = fc.u; tabD[idx] = fd.u;
    }
    for (int idx = tid; idx < 1024; idx += 256) {
        int l2 = idx & 63, nt = (idx >> 6) & 7, kc = idx >> 9;
        int col = nt * 16 + (l2 & 15);
        int kr  = kc * 32 + ((l2 >> 4) << 3);
        F8 f;
#pragma unroll
        for (int j = 0; j < 8; j++) f.f[j] = (_Float16)Wd1[(kr + j) * 128 + col];
        tabE[idx] = f.u;
    }
    // rank-1 V frags in registers (per lane, nt = 0..3)
    F8 vreg[4];
#pragma unroll
    for (int nt = 0; nt < 4; nt++) {
        int col = nt * 16 + m;
#pragma unroll
        for (int j = 0; j < 8; j++) vreg[nt].f[j] = (_Float16)0.f;
        if (quad == 0) {
            vreg[nt].f[0] = (_Float16)bw[col];
            vreg[nt].f[1] = (_Float16)bk[col];
            vreg[nt].f[2] = (_Float16)Wk[col];
            vreg[nt].f[3] = (_Float16)Wk[64 + col];
            vreg[nt].f[4] = (_Float16)Wk[128 + col];
            vreg[nt].f[5] = (_Float16)Wk[192 + col];
            vreg[nt].f[6] = (_Float16)Wk[256 + col];
        }
    }
    __syncthreads();

    const uint4* h8 = (const uint4*)h16;
    __half* wt = &h2t[wave * 16 * 72];
    float bd2v = bd2[0];

    int tile = blockIdx.x * 4 + wave;       // 1 tile per wave, 1024 blocks
    int base = tile * 16;
    int n = base + m;
    int2 cv = *(const int2*)&cnt[n << 1];
    float gix0 = grid[2 * n], giy0 = grid[2 * n + 1];

    // ---- inline gather: lane (quad,m) owns chunks quad and quad+4 ----
    float a0[8] = {0,0,0,0,0,0,0,0};
    float a1g[8] = {0,0,0,0,0,0,0,0};
    float sgx = 0.f, sgy = 0.f, sd = 0.f;
#pragma unroll
    for (int r = 0; r < 2; r++) {
        int dg = min((r == 0) ? cv.x : cv.y, CAPR);
        const unsigned short* sr = ssrc + ((size_t)n << 6) + (r << 5);
        for (int i = 0; i < dg; i += 4) {
            ushort4 sv = *(const ushort4*)&sr[i];
            int sx = sv.x, sy = sv.y, sz = sv.z, sw = sv.w;
            int rem = dg - i;
            if (rem < 4) {                  // clamp garbage to a valid index
                if (rem <= 1) sy = sx;
                if (rem <= 2) sz = sx;
                sw = (rem <= 3) ? sx : sw;
            }
            uint4 u;
            u = h8[(size_t)sx * 8 + quad];     acc8(a0, u);
            u = h8[(size_t)sx * 8 + 4 + quad]; acc8(a1g, u);
            if (rem > 1) {
                u = h8[(size_t)sy * 8 + quad];     acc8(a0, u);
                u = h8[(size_t)sy * 8 + 4 + quad]; acc8(a1g, u);
            }
            if (rem > 2) {
                u = h8[(size_t)sz * 8 + quad];     acc8(a0, u);
                u = h8[(size_t)sz * 8 + 4 + quad]; acc8(a1g, u);
            }
            if (rem > 3) {
                u = h8[(size_t)sw * 8 + quad];     acc8(a0, u);
                u = h8[(size_t)sw * 8 + 4 + quad]; acc8(a1g, u);
            }
            if (i + quad < dg) {            // one dist per lane quad 0..3
                int sj = (quad == 0) ? sx : (quad == 1) ? sy : (quad == 2) ? sz : sw;
                float2 g = *(const float2*)&grid[2 * sj];
                float dx = gix0 - g.x, dy = giy0 - g.y;
                sd += sqrtf(dx * dx + dy * dy);
                sgx += g.x; sgy += g.y;
            }
        }
    }
    // reduce dist/grid sums across the 4 lanes (quad) of node m
    sd  += __shfl_xor(sd, 16);  sd  += __shfl_xor(sd, 32);
    sgx += __shfl_xor(sgx, 16); sgx += __shfl_xor(sgx, 32);
    sgy += __shfl_xor(sgy, 16); sgy += __shfl_xor(sgy, 32);

    float deg = (float)(min(cv.x, CAPR) + min(cv.y, CAPR));
    float gix = gix0 * deg, giy = giy0 * deg;

    F8 ah0, ah1, as0, as1, ahd0, ahd1, au;
    ah0.u = h8[(size_t)n * 8 + quad];
    ah1.u = h8[(size_t)n * 8 + 4 + quad];
    as0.u = pack8(a0);                      // gather sum already in frag layout
    as1.u = pack8(a1g);
    _Float16 dh = (_Float16)deg;
#pragma unroll
    for (int j = 0; j < 8; j++) { ahd0.f[j] = ah0.f[j] * dh; ahd1.f[j] = ah1.f[j] * dh; }
    float z = (quad == 0) ? 1.f : 0.f;
    au.f[0] = (_Float16)z;          au.f[1] = (_Float16)(deg * z);
    au.f[2] = (_Float16)(sd * z);   au.f[3] = (_Float16)(gix * z);
    au.f[4] = (_Float16)(giy * z);  au.f[5] = (_Float16)(sgx * z);
    au.f[6] = (_Float16)(sgy * z);  au.f[7] = (_Float16)0.f;

    // phase A: update -> h2 tile in LDS (D layout: row quad*4+reg, col m+16nt)
#pragma unroll
    for (int nt = 0; nt < 4; nt++) {
        F8 bw0, bw1, bc0, bc1, bd0, bd1f;
        bw0.u = tabW[nt * 64 + lane];       bw1.u = tabW[256 + nt * 64 + lane];
        bc0.u = tabC[nt * 64 + lane];       bc1.u = tabC[256 + nt * 64 + lane];
        bd0.u = tabD[nt * 64 + lane];       bd1f.u = tabD[256 + nt * 64 + lane];
        v4f acc = {0.f, 0.f, 0.f, 0.f};
        acc = __builtin_amdgcn_mfma_f32_16x16x32_f16(au.v,   vreg[nt].v, acc, 0, 0, 0);
        acc = __builtin_amdgcn_mfma_f32_16x16x32_f16(ah0.v,  bw0.v,  acc, 0, 0, 0);
        acc = __builtin_amdgcn_mfma_f32_16x16x32_f16(ah1.v,  bw1.v,  acc, 0, 0, 0);
        acc = __builtin_amdgcn_mfma_f32_16x16x32_f16(ahd0.v, bc0.v,  acc, 0, 0, 0);
        acc = __builtin_amdgcn_mfma_f32_16x16x32_f16(ahd1.v, bc1.v,  acc, 0, 0, 0);
        acc = __builtin_amdgcn_mfma_f32_16x16x32_f16(as0.v,  bd0.v,  acc, 0, 0, 0);
        acc = __builtin_amdgcn_mfma_f32_16x16x32_f16(as1.v,  bd1f.v, acc, 0, 0, 0);
#pragma unroll
        for (int reg = 0; reg < 4; reg++)
            wt[(quad * 4 + reg) * 72 + m + 16 * nt] = __float2half(gelu(acc[reg]));
    }
    __syncthreads();   // h2 tile visible (uniform: every wave has 1 tile)

    // phase B: decode. A-frags of h2 from LDS row m.
    F8 dh0, dh1;
    dh0.u = *(const uint4*)&wt[m * 72 + quad * 8];
    dh1.u = *(const uint4*)&wt[m * 72 + 32 + quad * 8];
    float p[4] = {0.f, 0.f, 0.f, 0.f};
#pragma unroll
    for (int nt = 0; nt < 8; nt++) {
        int col = m + 16 * nt;
        float b = bd1[col];
        float w2 = Wd2[col];
        F8 b0, b1;
        b0.u = tabE[nt * 64 + lane];
        b1.u = tabE[512 + nt * 64 + lane];
        v4f acc = {b, b, b, b};
        acc = __builtin_amdgcn_mfma_f32_16x16x32_f16(dh0.v, b0.v, acc, 0, 0, 0);
        acc = __builtin_amdgcn_mfma_f32_16x16x32_f16(dh1.v, b1.v, acc, 0, 0, 0);
#pragma unroll
        for (int reg = 0; reg < 4; reg++) p[reg] += gelu(acc[reg]) * w2;
    }
#pragma unroll
    for (int reg = 0; reg < 4; reg++) {
        p[reg] += __shfl_xor(p[reg], 1);
        p[reg] += __shfl_xor(p[reg], 2);
        p[reg] += __shfl_xor(p[reg], 4);
        p[reg] += __shfl_xor(p[reg], 8);
    }
    if (m == 0) {
#pragma unroll
        for (int reg = 0; reg < 4; reg++)
            out[base + quad * 4 + reg] = p[reg] + bd2v;
    }
}

extern "C" void kernel_launch(void* const* d_in, const int* in_sizes, int n_in,
                              void* d_out, int out_size, void* d_ws, size_t ws_size,
                              hipStream_t stream)
{
    const float* x    = (const float*)d_in[0];
    const float* grid = (const float*)d_in[1];
    const int*   ei   = (const int*)d_in[2];
    const float* W1   = (const float*)d_in[3];
    const float* b1   = (const float*)d_in[4];
    const float* W2   = (const float*)d_in[5];
    const float* b2   = (const float*)d_in[6];
    const float* Wk   = (const float*)d_in[7];
    const float* bk   = (const float*)d_in[8];
    const float* Ww   = (const float*)d_in[9];
    const float* bw   = (const float*)d_in[10];
    const float* Wd1  = (const float*)d_in[11];
    const float* bd1  = (const float*)d_in[12];
    const float* Wd2  = (const float*)d_in[13];
    const float* bd2  = (const float*)d_in[14];
    float* out = (float*)d_out;

    int N = in_sizes[0] / 10;
    int E = in_sizes[2] / 2;

    char* ws = (char*)d_ws;
    size_t o_h16  = 0;
    size_t o_cnt  = o_h16 + (size_t)N * 64 * 2;
    size_t o_ssrc = o_cnt + (size_t)N * 2 * 4;

    __half* h16 = (__half*)(ws + o_h16);
    int*    cnt = (int*)  (ws + o_cnt);                    // N x 2 replica counters
    unsigned short* ssrc = (unsigned short*)(ws + o_ssrc); // N x 64 slots (2 x CAPR), u16

    hipMemsetAsync(cnt, 0, (size_t)N * 2 * 4, stream);

    int scatB = E / (256 * 4);           // 1024 scatter blocks = 8 partitions x 128 chunks
    int encB  = (N / 16) / 8;            // 512
    k_enc_scat<<<dim3(scatB + encB), dim3(256), 0, stream>>>(x, grid, W1, b1, W2, b2,
                                                             ei, cnt, ssrc, h16, N, E, scatB);
    int tiles = N / 16;                  // 4096; 4 tiles/block (1 per wave)
    k_gupdec<<<dim3(tiles / 4), dim3(256), 0, stream>>>(h16, ssrc, cnt, grid,
                                                        Wk, bk, Ww, bw,
                                                        Wd1, bd1, Wd2, bd2, out, N);
}

// Round 8
// 200.414 us; speedup vs baseline: 1.1219x; 1.1219x over previous
//
#include <hip/hip_runtime.h>
#include <hip/hip_fp16.h>

static __device__ __forceinline__ float gelu(float x) {
    return 0.5f * x * (1.0f + erff(x * 0.70710678118654752f));
}

#define CAPR 32   // slots per replica (2 replicas/node, Poisson(8) -> safe)

typedef _Float16 v8h __attribute__((ext_vector_type(8)));
typedef float    v4f __attribute__((ext_vector_type(4)));
typedef int      v4i __attribute__((ext_vector_type(4)));
union F8 { uint4 u; v8h v; _Float16 f[8]; };

static __device__ __forceinline__ void acc8(float* a, uint4 u) {
    float2 f0 = __half22float2(*(__half2*)&u.x);
    float2 f1 = __half22float2(*(__half2*)&u.y);
    float2 f2 = __half22float2(*(__half2*)&u.z);
    float2 f3 = __half22float2(*(__half2*)&u.w);
    a[0] += f0.x; a[1] += f0.y; a[2] += f1.x; a[3] += f1.y;
    a[4] += f2.x; a[5] += f2.y; a[6] += f3.x; a[7] += f3.y;
}

static __device__ __forceinline__ uint4 pack8(const float* v) {
    __half2 p0 = __floats2half2_rn(v[0], v[1]);
    __half2 p1 = __floats2half2_rn(v[2], v[3]);
    __half2 p2 = __floats2half2_rn(v[4], v[5]);
    __half2 p3 = __floats2half2_rn(v[6], v[7]);
    uint4 u;
    u.x = *(unsigned*)&p0; u.y = *(unsigned*)&p1;
    u.z = *(unsigned*)&p2; u.w = *(unsigned*)&p3;
    return u;
}

// ---- v8: r4's merged scatter+encoder (best-measured phase 1) + one extra
//      block that builds the update/decode fp16 MFMA frag tables in GLOBAL
//      memory. r7 showed gupdec fusion was neutral because 49KB of LDS
//      weight tables capped it at 12 waves/CU during the latency-bound
//      gather. The tables are block-invariant -> L2-broadcast global reads;
//      gupdec LDS drops to 9KB. ----
__global__ void __launch_bounds__(256, 4)
k_enc_scat(const float* __restrict__ x,
           const float* __restrict__ grid,
           const float* __restrict__ W1,
           const float* __restrict__ b1,
           const float* __restrict__ W2,
           const float* __restrict__ b2,
           const int* __restrict__ ei, int* __restrict__ cnt,
           unsigned short* __restrict__ ssrc,
           __half* __restrict__ h16,
           const float* __restrict__ Wk, const float* __restrict__ bk,
           const float* __restrict__ Ww, const float* __restrict__ bw,
           const float* __restrict__ Wd1, uint4* __restrict__ gtab,
           int N, int E, int scatB, int encB)
{
    __shared__ uint4 tabW2[1024];           // 16 KB
    __shared__ __half wmids[4 * 16 * 136];  // 17 KB
    int tid = threadIdx.x;

    if ((int)blockIdx.x < scatB) {
        int p = blockIdx.x & 7;             // dst partition (== XCD via %8 round-robin)
        int c = blockIdx.x >> 3;            // edge chunk
        const v4i* s4 = (const v4i*)ei;
        const v4i* d4 = (const v4i*)(ei + E);
        int g4 = (E / (scatB >> 3)) >> 2;   // int4 groups per chunk (2048)
        int base4 = c * g4;
        int shift = 31 - __clz(N >> 3);     // log2(N/8) = 13
#pragma unroll 8
        for (int g = 0; g < g4 / 256; g++) {
            int idx = base4 + g * 256 + tid;
            v4i d = __builtin_nontemporal_load(&d4[idx]);
            v4i s = __builtin_nontemporal_load(&s4[idx]);
            int q;
            if ((d[0] >> shift) == p) {
                q = atomicAdd(&cnt[(d[0] << 1) + 0], 1);
                if (q < CAPR) ssrc[((size_t)d[0] << 6) + q] = (unsigned short)s[0];
            }
            if ((d[1] >> shift) == p) {
                q = atomicAdd(&cnt[(d[1] << 1) + 1], 1);
                if (q < CAPR) ssrc[((size_t)d[1] << 6) + 32 + q] = (unsigned short)s[1];
            }
            if ((d[2] >> shift) == p) {
                q = atomicAdd(&cnt[(d[2] << 1) + 0], 1);
                if (q < CAPR) ssrc[((size_t)d[2] << 6) + q] = (unsigned short)s[2];
            }
            if ((d[3] >> shift) == p) {
                q = atomicAdd(&cnt[(d[3] << 1) + 1], 1);
                if (q < CAPR) ssrc[((size_t)d[3] << 6) + 32 + q] = (unsigned short)s[3];
            }
        }
        return;
    }

    if ((int)blockIdx.x == scatB + encB) {
        // ---- build global frag tables: gW[512] gC[512] gD[512] gE[1024] gV[256] ----
        uint4* gW = gtab;
        uint4* gC = gtab + 512;
        uint4* gD = gtab + 1024;
        uint4* gE = gtab + 1536;
        uint4* gV = gtab + 2560;
        for (int idx = tid; idx < 512; idx += 256) {
            int l2 = idx & 63, nt = (idx >> 6) & 3, kc = idx >> 8;
            int col = nt * 16 + (l2 & 15);
            int kr  = kc * 32 + ((l2 >> 4) << 3);
            F8 fw, fc, fd;
#pragma unroll
            for (int j = 0; j < 8; j++) {
                fw.f[j] = (_Float16)Ww[(kr + j) * 64 + col];
                fc.f[j] = (_Float16)Wk[(size_t)(5 + kr + j) * 64 + col];
                fd.f[j] = (_Float16)Wk[(size_t)(69 + kr + j) * 64 + col];
            }
            gW[idx] = fw.u; gC[idx] = fc.u; gD[idx] = fd.u;
        }
        for (int idx = tid; idx < 1024; idx += 256) {
            int l2 = idx & 63, nt = (idx >> 6) & 7, kc = idx >> 9;
            int col = nt * 16 + (l2 & 15);
            int kr  = kc * 32 + ((l2 >> 4) << 3);
            F8 f;
#pragma unroll
            for (int j = 0; j < 8; j++) f.f[j] = (_Float16)Wd1[(kr + j) * 128 + col];
            gE[idx] = f.u;
        }
        {
            int l2 = tid & 63, nt = tid >> 6;
            int col = nt * 16 + (l2 & 15);
            F8 fv;
#pragma unroll
            for (int j = 0; j < 8; j++) fv.f[j] = (_Float16)0.f;
            if ((l2 >> 4) == 0) {
                fv.f[0] = (_Float16)bw[col];
                fv.f[1] = (_Float16)bk[col];
                fv.f[2] = (_Float16)Wk[col];
                fv.f[3] = (_Float16)Wk[64 + col];
                fv.f[4] = (_Float16)Wk[128 + col];
                fv.f[5] = (_Float16)Wk[192 + col];
                fv.f[6] = (_Float16)Wk[256 + col];
            }
            gV[tid] = fv.u;
        }
        return;
    }

    // ---- encoder ----
    int eb = blockIdx.x - scatB;
    int lane = tid & 63, wave = tid >> 6;
    int m = lane & 15, quad = lane >> 4;

    F8 w1f[8];
#pragma unroll
    for (int nt = 0; nt < 8; nt++) {
        int col = nt * 16 + m;
        int k0 = quad << 3;
#pragma unroll
        for (int j = 0; j < 8; j++)
            w1f[nt].f[j] = (k0 + j < 12) ? (_Float16)W1[(k0 + j) * 128 + col] : (_Float16)0.f;
    }

    for (int idx = tid; idx < 1024; idx += 256) {     // W2 frags
        int l2 = idx & 63, nt = (idx >> 6) & 3, kc = idx >> 8;
        int col = nt * 16 + (l2 & 15);
        int k0 = kc * 32 + ((l2 >> 4) << 3);
        F8 f;
#pragma unroll
        for (int j = 0; j < 8; j++) f.f[j] = (_Float16)W2[(k0 + j) * 64 + col];
        tabW2[idx] = f.u;
    }
    __syncthreads();

    __half* wm = &wmids[wave * 16 * 136];

    for (int t = 0; t < 2; t++) {
        int tile = eb * 8 + wave * 2 + t;
        int base = tile * 16;
        int n = base + m;
        F8 a1;
#pragma unroll
        for (int j = 0; j < 8; j++) a1.f[j] = (_Float16)0.f;
        if (quad == 0) {
            float2 x0 = *(const float2*)&x[(size_t)n * 10 + 0];
            float2 x1 = *(const float2*)&x[(size_t)n * 10 + 2];
            float2 x2 = *(const float2*)&x[(size_t)n * 10 + 4];
            float2 x3 = *(const float2*)&x[(size_t)n * 10 + 6];
            a1.f[0] = (_Float16)x0.x; a1.f[1] = (_Float16)x0.y;
            a1.f[2] = (_Float16)x1.x; a1.f[3] = (_Float16)x1.y;
            a1.f[4] = (_Float16)x2.x; a1.f[5] = (_Float16)x2.y;
            a1.f[6] = (_Float16)x3.x; a1.f[7] = (_Float16)x3.y;
        } else if (quad == 1) {
            float2 x4 = *(const float2*)&x[(size_t)n * 10 + 8];
            float2 g  = *(const float2*)&grid[(size_t)n * 2];
            a1.f[0] = (_Float16)x4.x; a1.f[1] = (_Float16)x4.y;
            a1.f[2] = (_Float16)g.x;  a1.f[3] = (_Float16)g.y;
        }
#pragma unroll
        for (int nt = 0; nt < 8; nt++) {
            int col = nt * 16 + m;
            float b = b1[col];
            v4f acc = {b, b, b, b};
            acc = __builtin_amdgcn_mfma_f32_16x16x32_f16(a1.v, w1f[nt].v, acc, 0, 0, 0);
#pragma unroll
            for (int reg = 0; reg < 4; reg++)
                wm[(quad * 4 + reg) * 136 + col] = __float2half(gelu(acc[reg]));
        }
        __syncthreads();

        F8 a2[4];
#pragma unroll
        for (int kc = 0; kc < 4; kc++)
            a2[kc].u = *(const uint4*)&wm[m * 136 + kc * 32 + quad * 8];
#pragma unroll
        for (int nt = 0; nt < 4; nt++) {
            int col = nt * 16 + m;
            float b = b2[col];
            v4f acc = {b, b, b, b};
#pragma unroll
            for (int kc = 0; kc < 4; kc++) {
                F8 bf; bf.u = tabW2[kc * 256 + nt * 64 + lane];
                acc = __builtin_amdgcn_mfma_f32_16x16x32_f16(a2[kc].v, bf.v, acc, 0, 0, 0);
            }
#pragma unroll
            for (int reg = 0; reg < 4; reg++)
                h16[(size_t)(base + quad * 4 + reg) * 64 + col] = __float2half(acc[reg]);
        }
        __syncthreads();
    }
}

// ---- v8: k_gupdec with weight frags from GLOBAL (L2-broadcast). LDS = h2t
//      only (9 KB). Gather sum lands in registers in the as0/as1 A-frag
//      layout (r7 scheme); sum_h16/sum_g/sum_d round-trips stay deleted. ----
__global__ void __launch_bounds__(256, 4)
k_gupdec(const __half* __restrict__ h16,
         const unsigned short* __restrict__ ssrc,
         const int* __restrict__ cnt, const float* __restrict__ grid,
         const uint4* __restrict__ gtab,
         const float* __restrict__ bd1, const float* __restrict__ Wd2,
         const float* __restrict__ bd2,
         float* __restrict__ out, int N)
{
    __shared__ __half h2t[4 * 16 * 72];     // 9 KB: per-wave h2 tile (stride 72)
    int tid = threadIdx.x;
    int lane = tid & 63, wave = tid >> 6;
    int m = lane & 15, quad = lane >> 4;

    const uint4* gW = gtab;
    const uint4* gC = gtab + 512;
    const uint4* gD = gtab + 1024;
    const uint4* gE = gtab + 1536;
    const uint4* gV = gtab + 2560;

    const uint4* h8 = (const uint4*)h16;
    __half* wt = &h2t[wave * 16 * 72];
    float bd2v = bd2[0];

    int tile = blockIdx.x * 4 + wave;       // 1 tile per wave, 1024 blocks
    int base = tile * 16;
    int n = base + m;
    int2 cv = *(const int2*)&cnt[n << 1];
    float gix0 = grid[2 * n], giy0 = grid[2 * n + 1];

    // ---- inline gather: lane (quad,m) owns chunks quad and quad+4 ----
    float a0[8] = {0,0,0,0,0,0,0,0};
    float a1g[8] = {0,0,0,0,0,0,0,0};
    float sgx = 0.f, sgy = 0.f, sd = 0.f;
#pragma unroll
    for (int r = 0; r < 2; r++) {
        int dg = min((r == 0) ? cv.x : cv.y, CAPR);
        const unsigned short* sr = ssrc + ((size_t)n << 6) + (r << 5);
        for (int i = 0; i < dg; i += 4) {
            ushort4 sv = *(const ushort4*)&sr[i];
            int sx = sv.x, sy = sv.y, sz = sv.z, sw = sv.w;
            int rem = dg - i;
            if (rem < 4) {                  // clamp garbage to a valid index
                if (rem <= 1) sy = sx;
                if (rem <= 2) sz = sx;
                sw = (rem <= 3) ? sx : sw;
            }
            uint4 u;
            u = h8[(size_t)sx * 8 + quad];     acc8(a0, u);
            u = h8[(size_t)sx * 8 + 4 + quad]; acc8(a1g, u);
            if (rem > 1) {
                u = h8[(size_t)sy * 8 + quad];     acc8(a0, u);
                u = h8[(size_t)sy * 8 + 4 + quad]; acc8(a1g, u);
            }
            if (rem > 2) {
                u = h8[(size_t)sz * 8 + quad];     acc8(a0, u);
                u = h8[(size_t)sz * 8 + 4 + quad]; acc8(a1g, u);
            }
            if (rem > 3) {
                u = h8[(size_t)sw * 8 + quad];     acc8(a0, u);
                u = h8[(size_t)sw * 8 + 4 + quad]; acc8(a1g, u);
            }
            if (i + quad < dg) {            // one dist per lane quad 0..3
                int sj = (quad == 0) ? sx : (quad == 1) ? sy : (quad == 2) ? sz : sw;
                float2 g = *(const float2*)&grid[2 * sj];
                float dx = gix0 - g.x, dy = giy0 - g.y;
                sd += sqrtf(dx * dx + dy * dy);
                sgx += g.x; sgy += g.y;
            }
        }
    }
    // reduce dist/grid sums across the 4 lanes (quad) of node m
    sd  += __shfl_xor(sd, 16);  sd  += __shfl_xor(sd, 32);
    sgx += __shfl_xor(sgx, 16); sgx += __shfl_xor(sgx, 32);
    sgy += __shfl_xor(sgy, 16); sgy += __shfl_xor(sgy, 32);

    float deg = (float)(min(cv.x, CAPR) + min(cv.y, CAPR));
    float gix = gix0 * deg, giy = giy0 * deg;

    F8 ah0, ah1, as0, as1, ahd0, ahd1, au;
    ah0.u = h8[(size_t)n * 8 + quad];
    ah1.u = h8[(size_t)n * 8 + 4 + quad];
    as0.u = pack8(a0);                      // gather sum already in frag layout
    as1.u = pack8(a1g);
    _Float16 dh = (_Float16)deg;
#pragma unroll
    for (int j = 0; j < 8; j++) { ahd0.f[j] = ah0.f[j] * dh; ahd1.f[j] = ah1.f[j] * dh; }
    float z = (quad == 0) ? 1.f : 0.f;
    au.f[0] = (_Float16)z;          au.f[1] = (_Float16)(deg * z);
    au.f[2] = (_Float16)(sd * z);   au.f[3] = (_Float16)(gix * z);
    au.f[4] = (_Float16)(giy * z);  au.f[5] = (_Float16)(sgx * z);
    au.f[6] = (_Float16)(sgy * z);  au.f[7] = (_Float16)0.f;

    // phase A: update -> h2 tile in LDS (D layout: row quad*4+reg, col m+16nt)
#pragma unroll
    for (int nt = 0; nt < 4; nt++) {
        F8 bv, bw0, bw1, bc0, bc1, bd0, bd1f;
        bv.u  = gV[nt * 64 + lane];
        bw0.u = gW[nt * 64 + lane];       bw1.u = gW[256 + nt * 64 + lane];
        bc0.u = gC[nt * 64 + lane];       bc1.u = gC[256 + nt * 64 + lane];
        bd0.u = gD[nt * 64 + lane];       bd1f.u = gD[256 + nt * 64 + lane];
        v4f acc = {0.f, 0.f, 0.f, 0.f};
        acc = __builtin_amdgcn_mfma_f32_16x16x32_f16(au.v,   bv.v,   acc, 0, 0, 0);
        acc = __builtin_amdgcn_mfma_f32_16x16x32_f16(ah0.v,  bw0.v,  acc, 0, 0, 0);
        acc = __builtin_amdgcn_mfma_f32_16x16x32_f16(ah1.v,  bw1.v,  acc, 0, 0, 0);
        acc = __builtin_amdgcn_mfma_f32_16x16x32_f16(ahd0.v, bc0.v,  acc, 0, 0, 0);
        acc = __builtin_amdgcn_mfma_f32_16x16x32_f16(ahd1.v, bc1.v,  acc, 0, 0, 0);
        acc = __builtin_amdgcn_mfma_f32_16x16x32_f16(as0.v,  bd0.v,  acc, 0, 0, 0);
        acc = __builtin_amdgcn_mfma_f32_16x16x32_f16(as1.v,  bd1f.v, acc, 0, 0, 0);
#pragma unroll
        for (int reg = 0; reg < 4; reg++)
            wt[(quad * 4 + reg) * 72 + m + 16 * nt] = __float2half(gelu(acc[reg]));
    }
    __syncthreads();   // uniform (every wave has exactly 1 tile)

    // phase B: decode. A-frags of h2 from LDS row m.
    F8 dh0, dh1;
    dh0.u = *(const uint4*)&wt[m * 72 + quad * 8];
    dh1.u = *(const uint4*)&wt[m * 72 + 32 + quad * 8];
    float p[4] = {0.f, 0.f, 0.f, 0.f};
#pragma unroll
    for (int nt = 0; nt < 8; nt++) {
        int col = m + 16 * nt;
        float b = bd1[col];
        float w2 = Wd2[col];
        F8 b0, b1;
        b0.u = gE[nt * 64 + lane];
        b1.u = gE[512 + nt * 64 + lane];
        v4f acc = {b, b, b, b};
        acc = __builtin_amdgcn_mfma_f32_16x16x32_f16(dh0.v, b0.v, acc, 0, 0, 0);
        acc = __builtin_amdgcn_mfma_f32_16x16x32_f16(dh1.v, b1.v, acc, 0, 0, 0);
#pragma unroll
        for (int reg = 0; reg < 4; reg++) p[reg] += gelu(acc[reg]) * w2;
    }
#pragma unroll
    for (int reg = 0; reg < 4; reg++) {
        p[reg] += __shfl_xor(p[reg], 1);
        p[reg] += __shfl_xor(p[reg], 2);
        p[reg] += __shfl_xor(p[reg], 4);
        p[reg] += __shfl_xor(p[reg], 8);
    }
    if (m == 0) {
#pragma unroll
        for (int reg = 0; reg < 4; reg++)
            out[base + quad * 4 + reg] = p[reg] + bd2v;
    }
}

extern "C" void kernel_launch(void* const* d_in, const int* in_sizes, int n_in,
                              void* d_out, int out_size, void* d_ws, size_t ws_size,
                              hipStream_t stream)
{
    const float* x    = (const float*)d_in[0];
    const float* grid = (const float*)d_in[1];
    const int*   ei   = (const int*)d_in[2];
    const float* W1   = (const float*)d_in[3];
    const float* b1   = (const float*)d_in[4];
    const float* W2   = (const float*)d_in[5];
    const float* b2   = (const float*)d_in[6];
    const float* Wk   = (const float*)d_in[7];
    const float* bk   = (const float*)d_in[8];
    const float* Ww   = (const float*)d_in[9];
    const float* bw   = (const float*)d_in[10];
    const float* Wd1  = (const float*)d_in[11];
    const float* bd1  = (const float*)d_in[12];
    const float* Wd2  = (const float*)d_in[13];
    const float* bd2  = (const float*)d_in[14];
    float* out = (float*)d_out;

    int N = in_sizes[0] / 10;
    int E = in_sizes[2] / 2;

    char* ws = (char*)d_ws;
    size_t o_h16  = 0;
    size_t o_cnt  = o_h16 + (size_t)N * 64 * 2;
    size_t o_ssrc = o_cnt + (size_t)N * 2 * 4;
    size_t o_tab  = o_ssrc + (size_t)N * 64 * 2;

    __half* h16 = (__half*)(ws + o_h16);
    int*    cnt = (int*)  (ws + o_cnt);                    // N x 2 replica counters
    unsigned short* ssrc = (unsigned short*)(ws + o_ssrc); // N x 64 slots (2 x CAPR), u16
    uint4*  gtab = (uint4*)(ws + o_tab);                   // 2816 uint4 = 45 KB frag tables

    hipMemsetAsync(cnt, 0, (size_t)N * 2 * 4, stream);

    int scatB = E / (256 * 4);           // 1024 scatter blocks = 8 partitions x 128 chunks
    int encB  = (N / 16) / 8;            // 512
    k_enc_scat<<<dim3(scatB + encB + 1), dim3(256), 0, stream>>>(x, grid, W1, b1, W2, b2,
                                                                 ei, cnt, ssrc, h16,
                                                                 Wk, bk, Ww, bw, Wd1, gtab,
                                                                 N, E, scatB, encB);
    int tiles = N / 16;                  // 4096; 4 tiles/block (1 per wave)
    k_gupdec<<<dim3(tiles / 4), dim3(256), 0, stream>>>(h16, ssrc, cnt, grid, gtab,
                                                        bd1, Wd2, bd2, out, N);
}